// Round 1
// baseline (117.802 us; speedup 1.0000x reference)
//
#include <hip/hip_runtime.h>

#define TPB 256

// ---------------------------------------------------------------------------
// Batched 3x3 QR (LAPACK Householder convention) to orthonormalize rows.
// A = Phi_P[i]^T ; geqrf-style Householder; Q = H0 H1 H2 ; Phi[i] = Q^T.
// Must match LAPACK sign convention: beta = -copysign(norm, alpha), tau=0 when
// trailing norm is zero.
// ---------------------------------------------------------------------------
__global__ void qr_phi_kernel(const float* __restrict__ PhiP, float* __restrict__ Phi) {
    int i = threadIdx.x;
    if (i >= 16) return;
    float A[3][3];
    for (int r = 0; r < 3; ++r)
        for (int c = 0; c < 3; ++c)
            A[r][c] = PhiP[i * 9 + c * 3 + r];  // A = Phi_P[i]^T

    float V[3][3];
    float tau[3];
    for (int k = 0; k < 3; ++k) {
        float alpha = A[k][k];
        float xn2 = 0.f;
        for (int r = k + 1; r < 3; ++r) xn2 += A[r][k] * A[r][k];
        float t = 0.f;
        float v[3] = {0.f, 0.f, 0.f};
        v[k] = 1.f;
        if (xn2 > 0.f) {
            float beta = -copysignf(sqrtf(alpha * alpha + xn2), alpha);
            t = (beta - alpha) / beta;
            float inv = 1.f / (alpha - beta);
            for (int r = k + 1; r < 3; ++r) v[r] = A[r][k] * inv;
            // apply H = I - t v v^T to A[k:3, k:3]
            for (int c = k; c < 3; ++c) {
                float w = 0.f;
                for (int r = k; r < 3; ++r) w += v[r] * A[r][c];
                w *= t;
                for (int r = k; r < 3; ++r) A[r][c] -= w * v[r];
            }
        }
        tau[k] = t;
        for (int r = 0; r < 3; ++r) V[k][r] = v[r];
    }
    // Q = H0 H1 H2 * I
    float Q[3][3] = {{1.f, 0.f, 0.f}, {0.f, 1.f, 0.f}, {0.f, 0.f, 1.f}};
    for (int k = 2; k >= 0; --k) {
        for (int c = 0; c < 3; ++c) {
            float w = 0.f;
            for (int r = 0; r < 3; ++r) w += V[k][r] * Q[r][c];
            w *= tau[k];
            for (int r = 0; r < 3; ++r) Q[r][c] -= w * V[k][r];
        }
    }
    for (int r = 0; r < 3; ++r)
        for (int c = 0; c < 3; ++c)
            Phi[i * 9 + r * 3 + c] = Q[c][r];  // Phi = Q^T (orthonormal rows)
}

// ---------------------------------------------------------------------------
// Fused 3 levels. Thread t consumes in[27t .. 27t+27), emits:
//   level lvl   : 9 d1 -> out[M0 + 9t+g], 9 d2 -> out[2*M0 + 9t+g]
//   level lvl+1 : 3 d1 -> out[M1 + 3t+h], 3 d2 -> out[2*M1 + 3t+h]
//   level lvl+2 : d1 -> out[M2+t], d2 -> out[2*M2+t], avg -> avg_out[t]
// where M0 = 9*m2, M1 = 3*m2, M2 = m2 (m2 = number of threads = len(in)/27).
// LDS-staged so all global reads/writes are coalesced.
// ---------------------------------------------------------------------------
__global__ void fused3_kernel(const float* __restrict__ in,
                              float* __restrict__ out,
                              float* __restrict__ avg_out,
                              const float* __restrict__ Phi,
                              int lvl, int m2) {
    __shared__ float sIn[27 * TPB];
    __shared__ float sSt[9 * TPB];
    const int lt = threadIdx.x;
    const int blk = blockIdx.x;
    const long nIn = 27L * m2;
    const long baseIn = 27L * TPB * blk;

    float P[27];
#pragma unroll
    for (int j = 0; j < 27; ++j) P[j] = Phi[lvl * 9 + j];

    // coalesced global -> LDS
    if (baseIn + 27 * TPB <= nIn) {
        const float4* in4 = reinterpret_cast<const float4*>(in + baseIn);
        for (int i = lt; i < 27 * TPB / 4; i += TPB) {
            float4 v = in4[i];
            sIn[4 * i + 0] = v.x;
            sIn[4 * i + 1] = v.y;
            sIn[4 * i + 2] = v.z;
            sIn[4 * i + 3] = v.w;
        }
    } else {
        for (int i = lt; i < 27 * TPB; i += TPB) {
            long g = baseIn + i;
            sIn[i] = (g < nIn) ? in[g] : 0.f;
        }
    }
    __syncthreads();

    float f[27];
#pragma unroll
    for (int j = 0; j < 27; ++j) f[j] = sIn[27 * lt + j];

    float a[9], d1a[9], d2a[9];
#pragma unroll
    for (int g = 0; g < 9; ++g) {
        float x = f[3 * g], y = f[3 * g + 1], z = f[3 * g + 2];
        a[g]   = x * P[0] + y * P[1] + z * P[2];
        d1a[g] = x * P[3] + y * P[4] + z * P[5];
        d2a[g] = x * P[6] + y * P[7] + z * P[8];
    }
    float b[3], d1b[3], d2b[3];
#pragma unroll
    for (int h = 0; h < 3; ++h) {
        float x = a[3 * h], y = a[3 * h + 1], z = a[3 * h + 2];
        b[h]   = x * P[9]  + y * P[10] + z * P[11];
        d1b[h] = x * P[12] + y * P[13] + z * P[14];
        d2b[h] = x * P[15] + y * P[16] + z * P[17];
    }
    float cavg, d1c, d2c;
    {
        float x = b[0], y = b[1], z = b[2];
        cavg = x * P[18] + y * P[19] + z * P[20];
        d1c  = x * P[21] + y * P[22] + z * P[23];
        d2c  = x * P[24] + y * P[25] + z * P[26];
    }

    const long M0 = 9L * m2, M1 = 3L * m2, M2 = m2;

    // level lvl d1
#pragma unroll
    for (int g = 0; g < 9; ++g) sSt[9 * lt + g] = d1a[g];
    __syncthreads();
    {
        long base = 9L * TPB * blk;
        for (int i = lt; i < 9 * TPB; i += TPB) {
            long g = base + i;
            if (g < M0) out[M0 + g] = sSt[i];
        }
    }
    __syncthreads();
    // level lvl d2
#pragma unroll
    for (int g = 0; g < 9; ++g) sSt[9 * lt + g] = d2a[g];
    __syncthreads();
    {
        long base = 9L * TPB * blk;
        for (int i = lt; i < 9 * TPB; i += TPB) {
            long g = base + i;
            if (g < M0) out[2 * M0 + g] = sSt[i];
        }
    }
    __syncthreads();
    // level lvl+1 d1
#pragma unroll
    for (int h = 0; h < 3; ++h) sSt[3 * lt + h] = d1b[h];
    __syncthreads();
    {
        long base = 3L * TPB * blk;
        for (int i = lt; i < 3 * TPB; i += TPB) {
            long g = base + i;
            if (g < M1) out[M1 + g] = sSt[i];
        }
    }
    __syncthreads();
    // level lvl+1 d2
#pragma unroll
    for (int h = 0; h < 3; ++h) sSt[3 * lt + h] = d2b[h];
    __syncthreads();
    {
        long base = 3L * TPB * blk;
        for (int i = lt; i < 3 * TPB; i += TPB) {
            long g = base + i;
            if (g < M1) out[2 * M1 + g] = sSt[i];
        }
    }
    // level lvl+2 (already coalesced per-thread)
    const long t = (long)TPB * blk + lt;
    if (t < M2) {
        out[M2 + t]     = d1c;
        out[2 * M2 + t] = d2c;
        avg_out[t]      = cavg;
    }
}

// ---------------------------------------------------------------------------
// Tail: levels 9..15 in a single block through LDS ping-pong (input 3^7=2187).
// Writes out[0] = final average at the end.
// ---------------------------------------------------------------------------
__global__ void tail_kernel(const float* __restrict__ in, float* __restrict__ out,
                            const float* __restrict__ Phi) {
    __shared__ float s0[2187];
    __shared__ float s1[729];
    const int lt = threadIdx.x;
    for (int i = lt; i < 2187; i += TPB) s0[i] = in[i];
    __syncthreads();
    float* cur = s0;
    float* nxt = s1;
    int len = 2187;
    for (int lvl = 9; lvl < 16; ++lvl) {
        int m = len / 3;
        float p0 = Phi[lvl * 9 + 0], p1 = Phi[lvl * 9 + 1], p2 = Phi[lvl * 9 + 2];
        float q0 = Phi[lvl * 9 + 3], q1 = Phi[lvl * 9 + 4], q2 = Phi[lvl * 9 + 5];
        float r0 = Phi[lvl * 9 + 6], r1 = Phi[lvl * 9 + 7], r2 = Phi[lvl * 9 + 8];
        for (int t = lt; t < m; t += TPB) {
            float x = cur[3 * t], y = cur[3 * t + 1], z = cur[3 * t + 2];
            out[m + t]     = x * q0 + y * q1 + z * q2;
            out[2 * m + t] = x * r0 + y * r1 + z * r2;
            nxt[t]         = x * p0 + y * p1 + z * p2;
        }
        __syncthreads();
        float* tmp = cur; cur = nxt; nxt = tmp;
        len = m;
    }
    if (lt == 0) out[0] = cur[0];
}

extern "C" void kernel_launch(void* const* d_in, const int* in_sizes, int n_in,
                              void* d_out, int out_size, void* d_ws, size_t ws_size,
                              hipStream_t stream) {
    const float* f    = (const float*)d_in[0];   // 3^16 floats
    const float* PhiP = (const float*)d_in[1];   // 16*3*3 floats
    float* out = (float*)d_out;                  // 3^16 floats
    float* ws  = (float*)d_ws;

    // ws layout (floats): [0,144) Phi ; [256, 256+3^13) bufA ; then 3^10 bufB ; then 3^7 bufC
    float* Phi  = ws;
    float* bufA = ws + 256;
    float* bufB = bufA + 1594323;   // 3^13
    float* bufC = bufB + 59049;     // 3^10
    // total scratch ~6.6 MB

    qr_phi_kernel<<<1, 64, 0, stream>>>(PhiP, Phi);

    const int m2_0 = 1594323;  // 3^13 threads, levels 0-2
    fused3_kernel<<<(m2_0 + TPB - 1) / TPB, TPB, 0, stream>>>(f, out, bufA, Phi, 0, m2_0);

    const int m2_1 = 59049;    // 3^10 threads, levels 3-5
    fused3_kernel<<<(m2_1 + TPB - 1) / TPB, TPB, 0, stream>>>(bufA, out, bufB, Phi, 3, m2_1);

    const int m2_2 = 2187;     // 3^7 threads, levels 6-8
    fused3_kernel<<<(m2_2 + TPB - 1) / TPB, TPB, 0, stream>>>(bufB, out, bufC, Phi, 6, m2_2);

    tail_kernel<<<1, TPB, 0, stream>>>(bufC, out, Phi);
}

// Round 2
// 87.779 us; speedup vs baseline: 1.3420x; 1.3420x over previous
//
#include <hip/hip_runtime.h>

#define TPB 256

// lgkm-only barrier: waits LDS ops, does NOT drain global stores (HIP's
// __syncthreads emits s_waitcnt vmcnt(0) which serializes store latency).
__device__ __forceinline__ void block_sync_lds() {
    asm volatile("s_waitcnt lgkmcnt(0)" ::: "memory");
    __builtin_amdgcn_s_barrier();
    asm volatile("" ::: "memory");
}

// ---------------------------------------------------------------------------
// Batched 3x3 QR (LAPACK Householder convention) to orthonormalize rows.
// ---------------------------------------------------------------------------
__global__ void qr_phi_kernel(const float* __restrict__ PhiP, float* __restrict__ Phi) {
    int i = threadIdx.x;
    if (i >= 16) return;
    float A[3][3];
    for (int r = 0; r < 3; ++r)
        for (int c = 0; c < 3; ++c)
            A[r][c] = PhiP[i * 9 + c * 3 + r];  // A = Phi_P[i]^T

    float V[3][3];
    float tau[3];
    for (int k = 0; k < 3; ++k) {
        float alpha = A[k][k];
        float xn2 = 0.f;
        for (int r = k + 1; r < 3; ++r) xn2 += A[r][k] * A[r][k];
        float t = 0.f;
        float v[3] = {0.f, 0.f, 0.f};
        v[k] = 1.f;
        if (xn2 > 0.f) {
            float beta = -copysignf(sqrtf(alpha * alpha + xn2), alpha);
            t = (beta - alpha) / beta;
            float inv = 1.f / (alpha - beta);
            for (int r = k + 1; r < 3; ++r) v[r] = A[r][k] * inv;
            for (int c = k; c < 3; ++c) {
                float w = 0.f;
                for (int r = k; r < 3; ++r) w += v[r] * A[r][c];
                w *= t;
                for (int r = k; r < 3; ++r) A[r][c] -= w * v[r];
            }
        }
        tau[k] = t;
        for (int r = 0; r < 3; ++r) V[k][r] = v[r];
    }
    float Q[3][3] = {{1.f, 0.f, 0.f}, {0.f, 1.f, 0.f}, {0.f, 0.f, 1.f}};
    for (int k = 2; k >= 0; --k) {
        for (int c = 0; c < 3; ++c) {
            float w = 0.f;
            for (int r = 0; r < 3; ++r) w += V[k][r] * Q[r][c];
            w *= tau[k];
            for (int r = 0; r < 3; ++r) Q[r][c] -= w * V[k][r];
        }
    }
    for (int r = 0; r < 3; ++r)
        for (int c = 0; c < 3; ++c)
            Phi[i * 9 + r * 3 + c] = Q[c][r];  // Phi = Q^T
}

// ---------------------------------------------------------------------------
// Fused 3 levels, strided ownership: thread lt of block b owns level-0 triples
// i0 = 9*TPB*b + g*TPB + lt (g=0..8). All detail stores are register->global,
// coalesced (consecutive lanes -> consecutive addresses). Only the average
// chain goes through LDS (sA: level-1 elements, sB: level-2 elements).
// Stride-3 global loads are contiguous per-wave (768B region) -> L1-served.
// ---------------------------------------------------------------------------
__global__ void fused3_kernel(const float* __restrict__ in,
                              float* __restrict__ out,
                              float* __restrict__ avg_out,
                              const float* __restrict__ Phi,
                              int lvl, int m2) {
    __shared__ float sA[9 * TPB];
    __shared__ float sB[3 * TPB];
    const int lt = threadIdx.x;
    const long blk = blockIdx.x;
    const long N0 = 9L * m2;            // level-0 triples
    const long N1 = 3L * m2;            // level-1 triples
    const long N2 = m2;                 // level-2 triples
    const long M0 = 9L * m2, M1 = 3L * m2, M2 = m2;  // out section bases
    const long b9 = 9L * TPB * blk;
    const long b3 = 3L * TPB * blk;
    const long b1 = 1L * TPB * blk;

    float P[27];
#pragma unroll
    for (int j = 0; j < 27; ++j) P[j] = Phi[lvl * 9 + j];

    // ---- level lvl: load stride-3, compute, store details direct, avg->LDS
#pragma unroll
    for (int g = 0; g < 9; ++g) {
        long i0 = b9 + (long)g * TPB + lt;
        float x = 0.f, y = 0.f, z = 0.f;
        if (i0 < N0) {
            const float* p = in + 3 * i0;
            x = p[0]; y = p[1]; z = p[2];
        }
        float a  = x * P[0] + y * P[1] + z * P[2];
        float d1 = x * P[3] + y * P[4] + z * P[5];
        float d2 = x * P[6] + y * P[7] + z * P[8];
        if (i0 < N0) {
            __builtin_nontemporal_store(d1, out + M0 + i0);
            __builtin_nontemporal_store(d2, out + 2 * M0 + i0);
        }
        sA[g * TPB + lt] = a;
    }
    block_sync_lds();

    // ---- level lvl+1: read avg triples from LDS (stride-3, conflict-free)
#pragma unroll
    for (int h = 0; h < 3; ++h) {
        long i1 = b3 + (long)h * TPB + lt;
        int e = 3 * (h * TPB + lt);
        float x = sA[e], y = sA[e + 1], z = sA[e + 2];
        float b  = x * P[9]  + y * P[10] + z * P[11];
        float d1 = x * P[12] + y * P[13] + z * P[14];
        float d2 = x * P[15] + y * P[16] + z * P[17];
        if (i1 < N1) {
            __builtin_nontemporal_store(d1, out + M1 + i1);
            __builtin_nontemporal_store(d2, out + 2 * M1 + i1);
        }
        sB[h * TPB + lt] = b;
    }
    block_sync_lds();

    // ---- level lvl+2
    {
        long i2 = b1 + lt;
        float x = sB[3 * lt], y = sB[3 * lt + 1], z = sB[3 * lt + 2];
        float a  = x * P[18] + y * P[19] + z * P[20];
        float d1 = x * P[21] + y * P[22] + z * P[23];
        float d2 = x * P[24] + y * P[25] + z * P[26];
        if (i2 < N2) {
            __builtin_nontemporal_store(d1, out + M2 + i2);
            __builtin_nontemporal_store(d2, out + 2 * M2 + i2);
            avg_out[i2] = a;
        }
    }
}

// ---------------------------------------------------------------------------
// Tail: levels 9..15 in a single block via LDS ping-pong (input 3^7 = 2187).
// ---------------------------------------------------------------------------
__global__ void tail_kernel(const float* __restrict__ in, float* __restrict__ out,
                            const float* __restrict__ Phi) {
    __shared__ float s0[2187];
    __shared__ float s1[729];
    const int lt = threadIdx.x;
    for (int i = lt; i < 2187; i += TPB) s0[i] = in[i];
    __syncthreads();
    float* cur = s0;
    float* nxt = s1;
    int len = 2187;
    for (int lvl = 9; lvl < 16; ++lvl) {
        int m = len / 3;
        float p0 = Phi[lvl * 9 + 0], p1 = Phi[lvl * 9 + 1], p2 = Phi[lvl * 9 + 2];
        float q0 = Phi[lvl * 9 + 3], q1 = Phi[lvl * 9 + 4], q2 = Phi[lvl * 9 + 5];
        float r0 = Phi[lvl * 9 + 6], r1 = Phi[lvl * 9 + 7], r2 = Phi[lvl * 9 + 8];
        for (int t = lt; t < m; t += TPB) {
            float x = cur[3 * t], y = cur[3 * t + 1], z = cur[3 * t + 2];
            out[m + t]     = x * q0 + y * q1 + z * q2;
            out[2 * m + t] = x * r0 + y * r1 + z * r2;
            nxt[t]         = x * p0 + y * p1 + z * p2;
        }
        __syncthreads();
        float* tmp = cur; cur = nxt; nxt = tmp;
        len = m;
    }
    if (lt == 0) out[0] = cur[0];
}

extern "C" void kernel_launch(void* const* d_in, const int* in_sizes, int n_in,
                              void* d_out, int out_size, void* d_ws, size_t ws_size,
                              hipStream_t stream) {
    const float* f    = (const float*)d_in[0];   // 3^16 floats
    const float* PhiP = (const float*)d_in[1];   // 16*3*3 floats
    float* out = (float*)d_out;                  // 3^16 floats
    float* ws  = (float*)d_ws;

    float* Phi  = ws;
    float* bufA = ws + 256;
    float* bufB = bufA + 1594323;   // 3^13
    float* bufC = bufB + 59049;     // 3^10

    qr_phi_kernel<<<1, 64, 0, stream>>>(PhiP, Phi);

    const int m2_0 = 1594323;  // 3^13, levels 0-2
    fused3_kernel<<<(m2_0 + TPB - 1) / TPB, TPB, 0, stream>>>(f, out, bufA, Phi, 0, m2_0);

    const int m2_1 = 59049;    // 3^10, levels 3-5
    fused3_kernel<<<(m2_1 + TPB - 1) / TPB, TPB, 0, stream>>>(bufA, out, bufB, Phi, 3, m2_1);

    const int m2_2 = 2187;     // 3^7, levels 6-8
    fused3_kernel<<<(m2_2 + TPB - 1) / TPB, TPB, 0, stream>>>(bufB, out, bufC, Phi, 6, m2_2);

    tail_kernel<<<1, TPB, 0, stream>>>(bufC, out, Phi);
}

// Round 3
// 87.244 us; speedup vs baseline: 1.3503x; 1.0061x over previous
//
#include <hip/hip_runtime.h>

#define TPB 256

// Force a wave-uniform float into an SGPR (keeps Phi coeffs out of VGPRs).
__device__ __forceinline__ float sgpr(float x) {
    return __int_as_float(__builtin_amdgcn_readfirstlane(__float_as_int(x)));
}

// Gather element e (0..191) of a wave-held 192-float chunk, where lane s holds
// chunk[64*c + s] in register vc. 3 shuffles + 2 selects.
__device__ __forceinline__ float gather3(float v0, float v1, float v2, int e) {
    int s = e & 63;
    float t0 = __shfl(v0, s);
    float t1 = __shfl(v1, s);
    float t2 = __shfl(v2, s);
    int r = e >> 6;
    return r == 0 ? t0 : (r == 1 ? t1 : t2);
}

// ---------------------------------------------------------------------------
// Batched 3x3 QR (LAPACK Householder convention) to orthonormalize rows.
// ---------------------------------------------------------------------------
__global__ void qr_phi_kernel(const float* __restrict__ PhiP, float* __restrict__ Phi) {
    int i = threadIdx.x;
    if (i >= 16) return;
    float A[3][3];
    for (int r = 0; r < 3; ++r)
        for (int c = 0; c < 3; ++c)
            A[r][c] = PhiP[i * 9 + c * 3 + r];  // A = Phi_P[i]^T

    float V[3][3];
    float tau[3];
    for (int k = 0; k < 3; ++k) {
        float alpha = A[k][k];
        float xn2 = 0.f;
        for (int r = k + 1; r < 3; ++r) xn2 += A[r][k] * A[r][k];
        float t = 0.f;
        float v[3] = {0.f, 0.f, 0.f};
        v[k] = 1.f;
        if (xn2 > 0.f) {
            float beta = -copysignf(sqrtf(alpha * alpha + xn2), alpha);
            t = (beta - alpha) / beta;
            float inv = 1.f / (alpha - beta);
            for (int r = k + 1; r < 3; ++r) v[r] = A[r][k] * inv;
            for (int c = k; c < 3; ++c) {
                float w = 0.f;
                for (int r = k; r < 3; ++r) w += v[r] * A[r][c];
                w *= t;
                for (int r = k; r < 3; ++r) A[r][c] -= w * v[r];
            }
        }
        tau[k] = t;
        for (int r = 0; r < 3; ++r) V[k][r] = v[r];
    }
    float Q[3][3] = {{1.f, 0.f, 0.f}, {0.f, 1.f, 0.f}, {0.f, 0.f, 1.f}};
    for (int k = 2; k >= 0; --k) {
        for (int c = 0; c < 3; ++c) {
            float w = 0.f;
            for (int r = 0; r < 3; ++r) w += V[k][r] * Q[r][c];
            w *= tau[k];
            for (int r = 0; r < 3; ++r) Q[r][c] -= w * V[k][r];
        }
    }
    for (int r = 0; r < 3; ++r)
        for (int c = 0; c < 3; ++c)
            Phi[i * 9 + r * 3 + c] = Q[c][r];  // Phi = Q^T
}

// ---------------------------------------------------------------------------
// Fused 3 levels, all-register version. Each wave owns 576 consecutive level-0
// triples (9 rounds x 64). Loads: 3 perfectly-coalesced dword loads per round
// (wave reads 192 consecutive floats), triples formed in-register via shuffle.
// Averages stay wave-local in registers across levels (no LDS, no barriers).
// Detail stores are direct, coalesced, non-temporal (protect f's L3 residency).
// ---------------------------------------------------------------------------
__global__ __launch_bounds__(TPB) void fused3_kernel(
        const float* __restrict__ in, float* __restrict__ out,
        float* __restrict__ avg_out, const float* __restrict__ Phi,
        int lvl, int m2) {
    const int lane = threadIdx.x & 63;
    const int w    = threadIdx.x >> 6;
    const long N0 = 9L * m2, N1 = 3L * m2, N2 = m2;   // triple counts per level
    const long M0 = 9L * m2, M1 = 3L * m2, M2 = m2;   // out section bases
    const long T0 = 2304L * blockIdx.x + 576L * w;    // wave's first level-0 triple
    const long T1 = T0 / 3;
    const long T2 = T0 / 9;

    float P[27];
#pragma unroll
    for (int j = 0; j < 27; ++j) P[j] = sgpr(Phi[lvl * 9 + j]);

    float a[9];
    // ---- level lvl: 9 rounds in 3 groups of 3
#pragma unroll
    for (int gg = 0; gg < 3; ++gg) {
        bool fullgrp = (T0 + 64L * (3 * gg + 3) <= N0);  // wave-uniform
        if (fullgrp) {
            float v[3][3];
#pragma unroll
            for (int r = 0; r < 3; ++r) {
                long F = 3 * T0 + 192L * (3 * gg + r);
#pragma unroll
                for (int c = 0; c < 3; ++c) v[r][c] = in[F + 64 * c + lane];
            }
#pragma unroll
            for (int r = 0; r < 3; ++r) {
                int g = 3 * gg + r;
                float x = gather3(v[r][0], v[r][1], v[r][2], 3 * lane + 0);
                float y = gather3(v[r][0], v[r][1], v[r][2], 3 * lane + 1);
                float z = gather3(v[r][0], v[r][1], v[r][2], 3 * lane + 2);
                float av = x * P[0] + y * P[1] + z * P[2];
                float d1 = x * P[3] + y * P[4] + z * P[5];
                float d2 = x * P[6] + y * P[7] + z * P[8];
                long t = T0 + 64L * g + lane;
                __builtin_nontemporal_store(d1, out + M0 + t);
                __builtin_nontemporal_store(d2, out + 2 * M0 + t);
                a[g] = av;
            }
        } else {
            // boundary: per-lane ownership, predicated scalar loads/stores
#pragma unroll
            for (int r = 0; r < 3; ++r) {
                int g = 3 * gg + r;
                long t = T0 + 64L * g + lane;
                float x = 0.f, y = 0.f, z = 0.f;
                if (t < N0) {
                    const float* p = in + 3 * t;
                    x = p[0]; y = p[1]; z = p[2];
                }
                float av = x * P[0] + y * P[1] + z * P[2];
                float d1 = x * P[3] + y * P[4] + z * P[5];
                float d2 = x * P[6] + y * P[7] + z * P[8];
                if (t < N0) {
                    __builtin_nontemporal_store(d1, out + M0 + t);
                    __builtin_nontemporal_store(d2, out + 2 * M0 + t);
                }
                a[g] = av;   // 0 for invalid: never consumed by a valid level-1 triple
            }
        }
    }

    // ---- level lvl+1: 3 rounds, elements a[] are wave-local
    float b[3];
#pragma unroll
    for (int h = 0; h < 3; ++h) {
        float x = gather3(a[3 * h], a[3 * h + 1], a[3 * h + 2], 3 * lane + 0);
        float y = gather3(a[3 * h], a[3 * h + 1], a[3 * h + 2], 3 * lane + 1);
        float z = gather3(a[3 * h], a[3 * h + 1], a[3 * h + 2], 3 * lane + 2);
        float bv = x * P[9]  + y * P[10] + z * P[11];
        float d1 = x * P[12] + y * P[13] + z * P[14];
        float d2 = x * P[15] + y * P[16] + z * P[17];
        long j = T1 + 64L * h + lane;
        if (j < N1) {
            __builtin_nontemporal_store(d1, out + M1 + j);
            __builtin_nontemporal_store(d2, out + 2 * M1 + j);
        }
        b[h] = bv;
    }

    // ---- level lvl+2: 1 round
    {
        float x = gather3(b[0], b[1], b[2], 3 * lane + 0);
        float y = gather3(b[0], b[1], b[2], 3 * lane + 1);
        float z = gather3(b[0], b[1], b[2], 3 * lane + 2);
        float cv = x * P[18] + y * P[19] + z * P[20];
        float d1 = x * P[21] + y * P[22] + z * P[23];
        float d2 = x * P[24] + y * P[25] + z * P[26];
        long u = T2 + lane;
        if (u < N2) {
            __builtin_nontemporal_store(d1, out + M2 + u);
            __builtin_nontemporal_store(d2, out + 2 * M2 + u);
            avg_out[u] = cv;   // regular store: keep avg chain L2/L3-resident
        }
    }
}

// ---------------------------------------------------------------------------
// Tail: levels 9..15 in a single block via LDS ping-pong (input 3^7 = 2187).
// ---------------------------------------------------------------------------
__global__ void tail_kernel(const float* __restrict__ in, float* __restrict__ out,
                            const float* __restrict__ Phi) {
    __shared__ float s0[2187];
    __shared__ float s1[729];
    const int lt = threadIdx.x;
    for (int i = lt; i < 2187; i += TPB) s0[i] = in[i];
    __syncthreads();
    float* cur = s0;
    float* nxt = s1;
    int len = 2187;
    for (int lvl = 9; lvl < 16; ++lvl) {
        int m = len / 3;
        float p0 = Phi[lvl * 9 + 0], p1 = Phi[lvl * 9 + 1], p2 = Phi[lvl * 9 + 2];
        float q0 = Phi[lvl * 9 + 3], q1 = Phi[lvl * 9 + 4], q2 = Phi[lvl * 9 + 5];
        float r0 = Phi[lvl * 9 + 6], r1 = Phi[lvl * 9 + 7], r2 = Phi[lvl * 9 + 8];
        for (int t = lt; t < m; t += TPB) {
            float x = cur[3 * t], y = cur[3 * t + 1], z = cur[3 * t + 2];
            out[m + t]     = x * q0 + y * q1 + z * q2;
            out[2 * m + t] = x * r0 + y * r1 + z * r2;
            nxt[t]         = x * p0 + y * p1 + z * p2;
        }
        __syncthreads();
        float* tmp = cur; cur = nxt; nxt = tmp;
        len = m;
    }
    if (lt == 0) out[0] = cur[0];
}

extern "C" void kernel_launch(void* const* d_in, const int* in_sizes, int n_in,
                              void* d_out, int out_size, void* d_ws, size_t ws_size,
                              hipStream_t stream) {
    const float* f    = (const float*)d_in[0];   // 3^16 floats
    const float* PhiP = (const float*)d_in[1];   // 16*3*3 floats
    float* out = (float*)d_out;                  // 3^16 floats
    float* ws  = (float*)d_ws;

    float* Phi  = ws;
    float* bufA = ws + 256;
    float* bufB = bufA + 1594323;   // 3^13
    float* bufC = bufB + 59049;     // 3^10

    qr_phi_kernel<<<1, 64, 0, stream>>>(PhiP, Phi);

    const int m2_0 = 1594323;  // 3^13, levels 0-2
    fused3_kernel<<<(m2_0 + TPB - 1) / TPB, TPB, 0, stream>>>(f, out, bufA, Phi, 0, m2_0);

    const int m2_1 = 59049;    // 3^10, levels 3-5
    fused3_kernel<<<(m2_1 + TPB - 1) / TPB, TPB, 0, stream>>>(bufA, out, bufB, Phi, 3, m2_1);

    const int m2_2 = 2187;     // 3^7, levels 6-8
    fused3_kernel<<<(m2_2 + TPB - 1) / TPB, TPB, 0, stream>>>(bufB, out, bufC, Phi, 6, m2_2);

    tail_kernel<<<1, TPB, 0, stream>>>(bufC, out, Phi);
}

// Round 4
// 85.554 us; speedup vs baseline: 1.3769x; 1.0198x over previous
//
#include <hip/hip_runtime.h>

#define TPB 256

// Force a wave-uniform float into an SGPR.
__device__ __forceinline__ float sgpr(float x) {
    return __int_as_float(__builtin_amdgcn_readfirstlane(__float_as_int(x)));
}

// Gather element e (0..191) of a wave-held 192-float chunk, where lane s holds
// chunk[64*c + s] in register vc.
__device__ __forceinline__ float gather3(float v0, float v1, float v2, int e) {
    int s = e & 63;
    float t0 = __shfl(v0, s);
    float t1 = __shfl(v1, s);
    float t2 = __shfl(v2, s);
    int r = e >> 6;
    return r == 0 ? t0 : (r == 1 ? t1 : t2);
}

// ---------------------------------------------------------------------------
// 3x3 QR (LAPACK Householder convention), inlined per-kernel.
// M = Phi_P[level] row-major; P out = Phi[level] row-major (orthonormal rows).
// ---------------------------------------------------------------------------
__device__ __forceinline__ void qr3(const float* __restrict__ M, float* __restrict__ P) {
    float A[3][3];
#pragma unroll
    for (int r = 0; r < 3; ++r)
#pragma unroll
        for (int c = 0; c < 3; ++c)
            A[r][c] = M[c * 3 + r];  // A = Phi_P^T

    float V[3][3], tau[3];
#pragma unroll
    for (int k = 0; k < 3; ++k) {
        float alpha = A[k][k];
        float xn2 = 0.f;
#pragma unroll
        for (int r = k + 1; r < 3; ++r) xn2 += A[r][k] * A[r][k];
        float t = 0.f;
        float v[3] = {0.f, 0.f, 0.f};
        v[k] = 1.f;
        if (xn2 > 0.f) {
            float beta = -copysignf(sqrtf(alpha * alpha + xn2), alpha);
            t = (beta - alpha) / beta;
            float inv = 1.f / (alpha - beta);
#pragma unroll
            for (int r = k + 1; r < 3; ++r) v[r] = A[r][k] * inv;
#pragma unroll
            for (int c = 0; c < 3; ++c) {
                if (c < k) continue;
                float w = 0.f;
#pragma unroll
                for (int r = 0; r < 3; ++r) if (r >= k) w += v[r] * A[r][c];
                w *= t;
#pragma unroll
                for (int r = 0; r < 3; ++r) if (r >= k) A[r][c] -= w * v[r];
            }
        }
        tau[k] = t;
#pragma unroll
        for (int r = 0; r < 3; ++r) V[k][r] = v[r];
    }
    float Q[3][3] = {{1.f, 0.f, 0.f}, {0.f, 1.f, 0.f}, {0.f, 0.f, 1.f}};
#pragma unroll
    for (int k = 2; k >= 0; --k) {
#pragma unroll
        for (int c = 0; c < 3; ++c) {
            float w = 0.f;
#pragma unroll
            for (int r = 0; r < 3; ++r) w += V[k][r] * Q[r][c];
            w *= tau[k];
#pragma unroll
            for (int r = 0; r < 3; ++r) Q[r][c] -= w * V[k][r];
        }
    }
#pragma unroll
    for (int r = 0; r < 3; ++r)
#pragma unroll
        for (int c = 0; c < 3; ++c)
            P[r * 3 + c] = Q[c][r];  // Phi = Q^T
}

// ---------------------------------------------------------------------------
// Fused 3 levels. Wave owns 576 consecutive level-0 triples. Interior waves:
// all 27 coalesced dword loads issued up front (single straight-line region,
// no branches between them -> deep MLP), QR computed redundantly in-lane while
// loads are in flight, then 9 shuffle-regroup + store rounds. Averages stay
// wave-local in registers across all 3 levels (no LDS, no barriers).
// ---------------------------------------------------------------------------
__global__ __launch_bounds__(TPB) void fused3_kernel(
        const float* __restrict__ in, float* __restrict__ out,
        float* __restrict__ avg_out, const float* __restrict__ PhiP,
        int lvl, int m2) {
    const int lane = threadIdx.x & 63;
    const int w    = threadIdx.x >> 6;
    const long N0 = 9L * m2, N1 = 3L * m2, N2 = m2;
    const long M0 = 9L * m2, M1 = 3L * m2, M2 = m2;
    const long T0 = 2304L * blockIdx.x + 576L * w;
    const long T1 = T0 / 3;
    const long T2 = T0 / 9;

    const bool interior = (T0 + 576 <= N0);  // wave-uniform

    // ---- issue all 27 input loads first (interior path)
    float v[9][3];
    if (interior) {
        const float* base = in + 3 * T0;
#pragma unroll
        for (int r = 0; r < 9; ++r)
#pragma unroll
            for (int c = 0; c < 3; ++c)
                v[r][c] = base[192L * r + 64 * c + lane];
    }

    // ---- QR for the 3 levels, redundant per-lane (overlaps load latency)
    float P[27];
    qr3(PhiP + 9L * lvl,       P + 0);
    qr3(PhiP + 9L * (lvl + 1), P + 9);
    qr3(PhiP + 9L * (lvl + 2), P + 18);
#pragma unroll
    for (int j = 0; j < 27; ++j) P[j] = sgpr(P[j]);

    float a[9];
    if (interior) {
#pragma unroll
        for (int g = 0; g < 9; ++g) {
            float x = gather3(v[g][0], v[g][1], v[g][2], 3 * lane + 0);
            float y = gather3(v[g][0], v[g][1], v[g][2], 3 * lane + 1);
            float z = gather3(v[g][0], v[g][1], v[g][2], 3 * lane + 2);
            float av = x * P[0] + y * P[1] + z * P[2];
            float d1 = x * P[3] + y * P[4] + z * P[5];
            float d2 = x * P[6] + y * P[7] + z * P[8];
            long t = T0 + 64L * g + lane;
            __builtin_nontemporal_store(d1, out + M0 + t);
            __builtin_nontemporal_store(d2, out + 2 * M0 + t);
            a[g] = av;
        }
    } else {
        // boundary wave (at most one per kernel): predicated scalar path
#pragma unroll
        for (int g = 0; g < 9; ++g) {
            long t = T0 + 64L * g + lane;
            float x = 0.f, y = 0.f, z = 0.f;
            if (t < N0) {
                const float* p = in + 3 * t;
                x = p[0]; y = p[1]; z = p[2];
            }
            float av = x * P[0] + y * P[1] + z * P[2];
            float d1 = x * P[3] + y * P[4] + z * P[5];
            float d2 = x * P[6] + y * P[7] + z * P[8];
            if (t < N0) {
                __builtin_nontemporal_store(d1, out + M0 + t);
                __builtin_nontemporal_store(d2, out + 2 * M0 + t);
            }
            a[g] = av;
        }
    }

    // ---- level lvl+1: wave-local regroup
    float b[3];
#pragma unroll
    for (int h = 0; h < 3; ++h) {
        float x = gather3(a[3 * h], a[3 * h + 1], a[3 * h + 2], 3 * lane + 0);
        float y = gather3(a[3 * h], a[3 * h + 1], a[3 * h + 2], 3 * lane + 1);
        float z = gather3(a[3 * h], a[3 * h + 1], a[3 * h + 2], 3 * lane + 2);
        float bv = x * P[9]  + y * P[10] + z * P[11];
        float d1 = x * P[12] + y * P[13] + z * P[14];
        float d2 = x * P[15] + y * P[16] + z * P[17];
        long j = T1 + 64L * h + lane;
        if (j < N1) {
            __builtin_nontemporal_store(d1, out + M1 + j);
            __builtin_nontemporal_store(d2, out + 2 * M1 + j);
        }
        b[h] = bv;
    }

    // ---- level lvl+2
    {
        float x = gather3(b[0], b[1], b[2], 3 * lane + 0);
        float y = gather3(b[0], b[1], b[2], 3 * lane + 1);
        float z = gather3(b[0], b[1], b[2], 3 * lane + 2);
        float cv = x * P[18] + y * P[19] + z * P[20];
        float d1 = x * P[21] + y * P[22] + z * P[23];
        float d2 = x * P[24] + y * P[25] + z * P[26];
        long u = T2 + lane;
        if (u < N2) {
            __builtin_nontemporal_store(d1, out + M2 + u);
            __builtin_nontemporal_store(d2, out + 2 * M2 + u);
            avg_out[u] = cv;
        }
    }
}

// ---------------------------------------------------------------------------
// Tail: levels 9..15, one block of 1024 threads, LDS ping-pong.
// QR for the 7 levels computed by 7 parallel lanes of wave 0.
// ---------------------------------------------------------------------------
#define TTPB 1024
__global__ __launch_bounds__(TTPB) void tail_kernel(
        const float* __restrict__ in, float* __restrict__ out,
        const float* __restrict__ PhiP) {
    __shared__ float s0[2187];
    __shared__ float s1[729];
    __shared__ float sPhi[63];
    const int lt = threadIdx.x;

    for (int i = lt; i < 2187; i += TTPB) s0[i] = in[i];
    if (lt < 7) {
        float P[9];
        qr3(PhiP + 9L * (9 + lt), P);
#pragma unroll
        for (int j = 0; j < 9; ++j) sPhi[lt * 9 + j] = P[j];
    }
    __syncthreads();

    float* cur = s0;
    float* nxt = s1;
    int len = 2187;
#pragma unroll
    for (int L = 0; L < 7; ++L) {
        int m = len / 3;
        float p0 = sPhi[L * 9 + 0], p1 = sPhi[L * 9 + 1], p2 = sPhi[L * 9 + 2];
        float q0 = sPhi[L * 9 + 3], q1 = sPhi[L * 9 + 4], q2 = sPhi[L * 9 + 5];
        float r0 = sPhi[L * 9 + 6], r1 = sPhi[L * 9 + 7], r2 = sPhi[L * 9 + 8];
        for (int t = lt; t < m; t += TTPB) {
            float x = cur[3 * t], y = cur[3 * t + 1], z = cur[3 * t + 2];
            out[m + t]     = x * q0 + y * q1 + z * q2;
            out[2 * m + t] = x * r0 + y * r1 + z * r2;
            nxt[t]         = x * p0 + y * p1 + z * p2;
        }
        // LDS-only barrier (don't drain the global detail stores)
        asm volatile("s_waitcnt lgkmcnt(0)" ::: "memory");
        __builtin_amdgcn_s_barrier();
        float* tmp = cur; cur = nxt; nxt = tmp;
        len = m;
    }
    if (lt == 0) out[0] = cur[0];
}

extern "C" void kernel_launch(void* const* d_in, const int* in_sizes, int n_in,
                              void* d_out, int out_size, void* d_ws, size_t ws_size,
                              hipStream_t stream) {
    const float* f    = (const float*)d_in[0];   // 3^16 floats
    const float* PhiP = (const float*)d_in[1];   // 16*3*3 floats
    float* out = (float*)d_out;                  // 3^16 floats
    float* ws  = (float*)d_ws;

    float* bufA = ws;                // 3^13 floats
    float* bufB = bufA + 1594323;    // 3^10 floats
    float* bufC = bufB + 59049;      // 3^7  floats

    const int m2_0 = 1594323;  // 3^13, levels 0-2
    fused3_kernel<<<(m2_0 + TPB - 1) / TPB, TPB, 0, stream>>>(f, out, bufA, PhiP, 0, m2_0);

    const int m2_1 = 59049;    // 3^10, levels 3-5
    fused3_kernel<<<(m2_1 + TPB - 1) / TPB, TPB, 0, stream>>>(bufA, out, bufB, PhiP, 3, m2_1);

    const int m2_2 = 2187;     // 3^7, levels 6-8
    fused3_kernel<<<(m2_2 + TPB - 1) / TPB, TPB, 0, stream>>>(bufB, out, bufC, PhiP, 6, m2_2);

    tail_kernel<<<1, TTPB, 0, stream>>>(bufC, out, PhiP);
}